// Round 7
// baseline (392.907 us; speedup 1.0000x reference)
//
#include <hip/hip_runtime.h>
#include <math.h>

#define NPTS 8192
#define TPB  256          // threads per block, pair kernels
#define QPL  2            // queries per lane
#define TILE 64           // points staged per LDS tile (64 * 64B = 4 KB as f16)
#define TPM  256          // threads per block, merge kernels

typedef _Float16 h2 __attribute__((ext_vector_type(2)));

static __device__ __forceinline__ h2 hmax2(h2 a, h2 b) {
#if __has_builtin(__builtin_elementwise_max)
    return __builtin_elementwise_max(a, b);
#else
    h2 r; r.x = a.x > b.x ? a.x : b.x; r.y = a.y > b.y ? a.y : b.y; return r;
#endif
}

static __device__ __forceinline__ h2 habs2(h2 a) {
    unsigned u = __builtin_bit_cast(unsigned, a) & 0x7FFF7FFFu;  // one v_and_b32
    return __builtin_bit_cast(h2, u);
}

// Branchless sorted-descending top-4 insert (7 ops, f32).
__device__ __forceinline__ void ins4(float d, float& t0, float& t1, float& t2, float& t3) {
    float n0 = fminf(t0, d);  t0 = fmaxf(t0, d);
    float n1 = fminf(t1, n0); t1 = fmaxf(t1, n0);
    float n2 = fminf(t2, n1); t2 = fmaxf(t2, n1);
    t3 = fmaxf(t3, n2);
}

__device__ double digamma_d(double x) {
    double r = 0.0;
    while (x < 6.0) { r -= 1.0 / x; x += 1.0; }
    double f = 1.0 / (x * x);
    double t = f * (1.0/12.0 - f * (1.0/120.0 - f * (1.0/252.0 - f * (1.0/240.0 - f * (1.0/132.0)))));
    return r + log(x) - 0.5 / x - t;
}

// ---------------------------------------------------------------------------
// K0: convert f32 inputs to f16 (half2-packed). idx over NPTS*16/4 float4s.
// ---------------------------------------------------------------------------
__global__ __launch_bounds__(TPM) void cvt_kernel(
    const float* __restrict__ x, const float* __restrict__ y,
    h2* __restrict__ xh, h2* __restrict__ yh)
{
    int idx = blockIdx.x * TPM + threadIdx.x;   // < NPTS*16/4 = 32768
    float4 vx = reinterpret_cast<const float4*>(x)[idx];
    float4 vy = reinterpret_cast<const float4*>(y)[idx];
    h2 a; a.x = (_Float16)vx.x; a.y = (_Float16)vx.y;
    h2 b; b.x = (_Float16)vx.z; b.y = (_Float16)vx.w;
    h2 c; c.x = (_Float16)vy.x; c.y = (_Float16)vy.y;
    h2 d; d.x = (_Float16)vy.z; d.y = (_Float16)vy.w;
    xh[2*idx] = a; xh[2*idx+1] = b;
    yh[2*idx] = c; yh[2*idx+1] = d;
}

// Unpack a uint4 (8 halves) into 4 half2s at dst.
static __device__ __forceinline__ void unpack8(h2* dst, uint4 w) {
    dst[0] = __builtin_bit_cast(h2, w.x);
    dst[1] = __builtin_bit_cast(h2, w.y);
    dst[2] = __builtin_bit_cast(h2, w.z);
    dst[3] = __builtin_bit_cast(h2, w.w);
}

// Load query q as 16 half2s (x dims 0..7, y dims 8..15).
static __device__ __forceinline__ void load_query_h(
    h2* qh, const h2* __restrict__ xh, const h2* __restrict__ yh, int q)
{
    const uint4* qx = reinterpret_cast<const uint4*>(xh) + (size_t)q * 2;
    const uint4* qy = reinterpret_cast<const uint4*>(yh) + (size_t)q * 2;
    unpack8(qh + 0,  qx[0]);
    unpack8(qh + 4,  qx[1]);
    unpack8(qh + 8,  qy[0]);
    unpack8(qh + 12, qy[1]);
}

// Cooperative stage of TILE f16 points into LDS.
// Layout: ptsh[pt*4 + c]: c<2 = x (8 halves each), c>=2 = y. TPB == TILE*4.
static __device__ __forceinline__ void stage_tile_h(
    uint4* ptsh, const h2* __restrict__ xh, const h2* __restrict__ yh, int jt)
{
    int li = threadIdx.x;               // 0 .. TILE*4-1
    int pt = li >> 2, c = li & 3;
    const uint4* src = (c < 2)
        ? reinterpret_cast<const uint4*>(xh) + (size_t)(jt + pt) * 2 + c
        : reinterpret_cast<const uint4*>(yh) + (size_t)(jt + pt) * 2 + (c - 2);
    ptsh[li] = *src;
}

// ---------------------------------------------------------------------------
// K1: per-query partial top-4 of joint Chebyshev distance over a point split.
// grid = (NPTS/(TPB*QPL), Sk). f16 points in LDS: 4 ds_read_b128 per pair-iter.
// ---------------------------------------------------------------------------
__global__ __launch_bounds__(TPB, 2) void knn_part_kernel(
    const h2* __restrict__ xh, const h2* __restrict__ yh,
    float4* __restrict__ part, int pps)
{
    __shared__ uint4 ptsh[TILE * 4];
    h2 qh[QPL][16];
    float t0[QPL], t1[QPL], t2[QPL], t3[QPL];
    #pragma unroll
    for (int u = 0; u < QPL; ++u) {
        load_query_h(qh[u], xh, yh, blockIdx.x * (TPB * QPL) + threadIdx.x + u * TPB);
        t0[u] = t1[u] = t2[u] = t3[u] = -1.0f;
    }

    const int j0 = blockIdx.y * pps;
    for (int jt = j0; jt < j0 + pps; jt += TILE) {
        stage_tile_h(ptsh, xh, yh, jt);
        __syncthreads();
        #pragma unroll 2
        for (int jj = 0; jj < TILE; ++jj) {
            h2 ph[16];
            unpack8(ph + 0,  ptsh[jj * 4 + 0]);   // wave-uniform broadcast
            unpack8(ph + 4,  ptsh[jj * 4 + 1]);
            unpack8(ph + 8,  ptsh[jj * 4 + 2]);
            unpack8(ph + 12, ptsh[jj * 4 + 3]);
            #pragma unroll
            for (int u = 0; u < QPL; ++u) {
                h2 t[16];
                #pragma unroll
                for (int k = 0; k < 16; ++k) t[k] = habs2(qh[u][k] - ph[k]);
                #pragma unroll
                for (int s = 8; s > 0; s >>= 1)
                    #pragma unroll
                    for (int k = 0; k < 8; ++k)
                        if (k < s) t[k] = hmax2(t[k], t[k + s]);
                float m = fmaxf((float)t[0].x, (float)t[0].y);
                ins4(m, t0[u], t1[u], t2[u], t3[u]);
            }
        }
        __syncthreads();
    }
    #pragma unroll
    for (int u = 0; u < QPL; ++u) {
        int q = blockIdx.x * (TPB * QPL) + threadIdx.x + u * TPB;
        part[(size_t)blockIdx.y * NPTS + q] = make_float4(t0[u], t1[u], t2[u], t3[u]);
    }
}

// ---------------------------------------------------------------------------
// K2: merge Sk partial top-4 lists per query -> radius r[q]
// ---------------------------------------------------------------------------
__global__ __launch_bounds__(TPM) void knn_merge_kernel(
    const float4* __restrict__ part, float* __restrict__ r, int S)
{
    const int q = blockIdx.x * TPM + threadIdx.x;
    float t0=-1.f,t1=-1.f,t2=-1.f,t3=-1.f;
    for (int s = 0; s < S; ++s) {
        float4 v = part[(size_t)s * NPTS + q];
        ins4(v.x, t0, t1, t2, t3);
        ins4(v.y, t0, t1, t2, t3);
        ins4(v.z, t0, t1, t2, t3);
        ins4(v.w, t0, t1, t2, t3);
    }
    r[q] = t3 - 1e-15f;
}

// ---------------------------------------------------------------------------
// K3: partial inclusive range counts in X and Y marginals (f16 pipeline).
// ---------------------------------------------------------------------------
__global__ __launch_bounds__(TPB, 2) void count_part_kernel(
    const h2* __restrict__ xh, const h2* __restrict__ yh,
    const float* __restrict__ r,
    unsigned short* __restrict__ cx, unsigned short* __restrict__ cy, int pps)
{
    __shared__ uint4 ptsh[TILE * 4];
    h2 qh[QPL][16];
    float rq[QPL];
    int nx[QPL], ny[QPL];
    #pragma unroll
    for (int u = 0; u < QPL; ++u) {
        int q = blockIdx.x * (TPB * QPL) + threadIdx.x + u * TPB;
        load_query_h(qh[u], xh, yh, q);
        rq[u] = r[q];
        nx[u] = ny[u] = 0;
    }

    const int j0 = blockIdx.y * pps;
    for (int jt = j0; jt < j0 + pps; jt += TILE) {
        stage_tile_h(ptsh, xh, yh, jt);
        __syncthreads();
        #pragma unroll 2
        for (int jj = 0; jj < TILE; ++jj) {
            h2 ph[16];
            unpack8(ph + 0,  ptsh[jj * 4 + 0]);   // wave-uniform broadcast
            unpack8(ph + 4,  ptsh[jj * 4 + 1]);
            unpack8(ph + 8,  ptsh[jj * 4 + 2]);
            unpack8(ph + 12, ptsh[jj * 4 + 3]);
            #pragma unroll
            for (int u = 0; u < QPL; ++u) {
                h2 t[16];
                #pragma unroll
                for (int k = 0; k < 16; ++k) t[k] = habs2(qh[u][k] - ph[k]);
                // x-marginal tree over t[0..7], y-marginal over t[8..15]
                #pragma unroll
                for (int s = 4; s > 0; s >>= 1)
                    #pragma unroll
                    for (int k = 0; k < 4; ++k)
                        if (k < s) {
                            t[k]     = hmax2(t[k],     t[k + s]);
                            t[8 + k] = hmax2(t[8 + k], t[8 + k + s]);
                        }
                float mx = fmaxf((float)t[0].x, (float)t[0].y);
                float my = fmaxf((float)t[8].x, (float)t[8].y);
                nx[u] += (mx <= rq[u]) ? 1 : 0;
                ny[u] += (my <= rq[u]) ? 1 : 0;
            }
        }
        __syncthreads();
    }
    #pragma unroll
    for (int u = 0; u < QPL; ++u) {
        int q = blockIdx.x * (TPB * QPL) + threadIdx.x + u * TPB;
        cx[(size_t)blockIdx.y * NPTS + q] = (unsigned short)nx[u];
        cy[(size_t)blockIdx.y * NPTS + q] = (unsigned short)ny[u];
    }
}

// ---------------------------------------------------------------------------
// K4: merge partial counts -> digamma(nx)+digamma(ny) per query (f64).
// ---------------------------------------------------------------------------
__global__ __launch_bounds__(TPM) void count_merge_kernel(
    const unsigned short* __restrict__ cx, const unsigned short* __restrict__ cy,
    double* __restrict__ dig, int S)
{
    const int q = blockIdx.x * TPM + threadIdx.x;
    int nx = 0, ny = 0;
    for (int s = 0; s < S; ++s) {
        nx += cx[(size_t)s * NPTS + q];
        ny += cy[(size_t)s * NPTS + q];
    }
    dig[q] = digamma_d((double)nx) + digamma_d((double)ny);
}

// ---------------------------------------------------------------------------
// K5: ans = psi(N) + psi(k) - mean(psi(nx)+psi(ny))
// (log/log2 terms of the reference cancel exactly in ans_x+ans_y-ans_xy;
//  only the counts affect the result, which is why f16 distances are safe)
// ---------------------------------------------------------------------------
__global__ __launch_bounds__(TPM) void final_kernel(
    const double* __restrict__ dig, float* __restrict__ out)
{
    __shared__ double sm[TPM];
    double s = 0.0;
    for (int i = threadIdx.x; i < NPTS; i += TPM) s += dig[i];
    sm[threadIdx.x] = s;
    __syncthreads();
    for (int w = TPM / 2; w > 0; w >>= 1) {
        if (threadIdx.x < w) sm[threadIdx.x] += sm[threadIdx.x + w];
        __syncthreads();
    }
    if (threadIdx.x == 0) {
        double ans = digamma_d((double)NPTS) + digamma_d(4.0) - sm[0] / (double)NPTS;
        out[0] = (float)ans;
    }
}

// ---------------------------------------------------------------------------
extern "C" void kernel_launch(void* const* d_in, const int* in_sizes, int n_in,
                              void* d_out, int out_size, void* d_ws, size_t ws_size,
                              hipStream_t stream)
{
    (void)in_sizes; (void)n_in; (void)out_size;
    const float* x = (const float*)d_in[0];
    const float* y = (const float*)d_in[1];
    float* out = (float*)d_out;

    // workspace: dig (NPTS f64) | r (NPTS f32) | xh,yh (NPTS*16 f16 each)
    //            | part (Sk*NPTS float4) | cx,cy (Sc*NPTS u16 each)
    char* ws = (char*)d_ws;
    double* dig = (double*)ws;
    float*  r   = (float*)(ws + (size_t)NPTS * 8);
    h2*     xh  = (h2*)(ws + (size_t)NPTS * 12);
    h2*     yh  = (h2*)(ws + (size_t)NPTS * 12 + (size_t)NPTS * 32);
    char*   p0  = ws + (size_t)NPTS * 12 + (size_t)NPTS * 64;   // 16B aligned

    int Sk = 128, Sc = 128;
    auto need = [&](int sk, int sc) {
        return (size_t)(p0 - ws) + (size_t)sk * NPTS * 16 + (size_t)sc * NPTS * 4;
    };
    while (Sk > 32 && need(Sk, Sc) > ws_size) { Sk >>= 1; Sc >>= 1; }

    float4* part = (float4*)p0;
    unsigned short* cx = (unsigned short*)(p0 + (size_t)Sk * NPTS * 16);
    unsigned short* cy = cx + (size_t)Sc * NPTS;

    const int pps_k = NPTS / Sk;   // multiple of TILE (=64) for Sk<=128
    const int pps_c = NPTS / Sc;

    cvt_kernel<<<NPTS * 16 / 4 / TPM, TPM, 0, stream>>>(x, y, xh, yh);

    dim3 gridK(NPTS / (TPB * QPL), Sk);   // (16,128) = 2048 blocks = 8192 waves
    dim3 gridC(NPTS / (TPB * QPL), Sc);
    knn_part_kernel<<<gridK, TPB, 0, stream>>>(xh, yh, part, pps_k);
    knn_merge_kernel<<<NPTS / TPM, TPM, 0, stream>>>(part, r, Sk);
    count_part_kernel<<<gridC, TPB, 0, stream>>>(xh, yh, r, cx, cy, pps_c);
    count_merge_kernel<<<NPTS / TPM, TPM, 0, stream>>>(cx, cy, dig, Sc);
    final_kernel<<<1, TPM, 0, stream>>>(dig, out);
}

// Round 8
// 216.800 us; speedup vs baseline: 1.8123x; 1.8123x over previous
//
#include <hip/hip_runtime.h>
#include <math.h>

#define NPTS 8192
#define TPB  256          // threads per block, knn kernel
#define QPL  2            // queries per lane
#define TILE 64           // points staged per LDS tile (8 KB f32)
#define TPM  256          // threads per block, merge/check kernels

__device__ __forceinline__ float fmax3(float a, float b, float c) {
    return fmaxf(fmaxf(a, b), c);   // folds to v_max3_f32 (abs modifiers at leaves)
}

// Branchless sorted-descending top-4 insert with index payload on levels 0-2.
// (level 3 value-only: only indices with value > t3 are ever needed)
__device__ __forceinline__ void ins4p(float d, int di,
    float& t0, float& t1, float& t2, float& t3,
    int& i0, int& i1, int& i2)
{
    bool c0 = d > t0;
    float v1 = fminf(t0, d); int j1 = c0 ? i0 : di;
    t0 = fmaxf(t0, d);       i0 = c0 ? di : i0;
    bool c1 = v1 > t1;
    float v2 = fminf(t1, v1); int j2 = c1 ? i1 : j1;
    t1 = fmaxf(t1, v1);       i1 = c1 ? j1 : i1;
    bool c2 = v2 > t2;
    float v3 = fminf(t2, v2);
    t2 = fmaxf(t2, v2);       i2 = c2 ? j2 : i2;
    t3 = fmaxf(t3, v3);
}

__device__ double digamma_d(double x) {
    double r = 0.0;
    while (x < 6.0) { r -= 1.0 / x; x += 1.0; }   // ψ(4) in final kernel only
    double f = 1.0 / (x * x);
    double t = f * (1.0/12.0 - f * (1.0/120.0 - f * (1.0/252.0 - f * (1.0/240.0 - f * (1.0/132.0)))));
    return r + log(x) - 0.5 / x - t;
}

// Cooperative stage of TILE points (x:16 + y:16 floats) into LDS.
// Layout: pts4[pt*8 + c], c<4 = x float4s, c>=4 = y float4s.
__device__ __forceinline__ void stage_tile(
    float4* pts4, const float* __restrict__ x, const float* __restrict__ y, int jt)
{
    #pragma unroll
    for (int i = 0; i < (TILE * 8) / TPB; ++i) {
        int li = i * TPB + threadIdx.x;
        int pt = li >> 3, c = li & 7;
        const float4* src = (c < 4)
            ? reinterpret_cast<const float4*>(x) + (size_t)(jt + pt) * 4 + c
            : reinterpret_cast<const float4*>(y) + (size_t)(jt + pt) * 4 + (c - 4);
        pts4[li] = *src;
    }
}

__device__ __forceinline__ void load_query(float* qv, const float* __restrict__ x,
                                           const float* __restrict__ y, int q)
{
    const float4* qx4 = reinterpret_cast<const float4*>(x) + (size_t)q * 4;
    const float4* qy4 = reinterpret_cast<const float4*>(y) + (size_t)q * 4;
    #pragma unroll
    for (int i = 0; i < 4; ++i) {
        float4 v = qx4[i];
        qv[4*i+0] = v.x; qv[4*i+1] = v.y; qv[4*i+2] = v.z; qv[4*i+3] = v.w;
        float4 w = qy4[i];
        qv[16+4*i+0] = w.x; qv[16+4*i+1] = w.y; qv[16+4*i+2] = w.z; qv[16+4*i+3] = w.w;
    }
}

// ---------------------------------------------------------------------------
// K1: per-query partial top-4 (values) + top-3 (indices) of joint Chebyshev
// distance over a point split. grid = (NPTS/(TPB*QPL), Sk). R4-validated
// shape: f32, QPL=2, TPB=256, TILE=64 — LDS-broadcast-bound at ~88 us.
// ---------------------------------------------------------------------------
__global__ __launch_bounds__(TPB, 2) void knn_part_kernel(
    const float* __restrict__ x, const float* __restrict__ y,
    float4* __restrict__ part_v, ushort4* __restrict__ part_i, int pps)
{
    __shared__ float4 pts4[TILE * 8];
    float qv[QPL][32];
    float t0[QPL], t1[QPL], t2[QPL], t3[QPL];
    int   i0[QPL], i1[QPL], i2[QPL];
    #pragma unroll
    for (int u = 0; u < QPL; ++u) {
        load_query(qv[u], x, y, blockIdx.x * (TPB * QPL) + threadIdx.x + u * TPB);
        t0[u] = t1[u] = t2[u] = t3[u] = -1.0f;
        i0[u] = i1[u] = i2[u] = 0;
    }

    const int j0 = blockIdx.y * pps;
    for (int jt = j0; jt < j0 + pps; jt += TILE) {
        stage_tile(pts4, x, y, jt);
        __syncthreads();
        #pragma unroll 2
        for (int jj = 0; jj < TILE; ++jj) {
            const float4* pj = &pts4[jj * 8];
            float m[QPL];
            #pragma unroll
            for (int u = 0; u < QPL; ++u) m[u] = 0.0f;   // distances >= 0
            #pragma unroll
            for (int i = 0; i < 8; ++i) {
                float4 v = pj[i];                         // wave-uniform broadcast
                #pragma unroll
                for (int u = 0; u < QPL; ++u) {
                    float d0 = qv[u][4*i+0] - v.x;
                    float d1 = qv[u][4*i+1] - v.y;
                    float d2 = qv[u][4*i+2] - v.z;
                    float d3 = qv[u][4*i+3] - v.w;
                    m[u] = fmax3(m[u], fmax3(fabsf(d0), fabsf(d1), fabsf(d2)), fabsf(d3));
                }
            }
            const int di = jt + jj;
            #pragma unroll
            for (int u = 0; u < QPL; ++u)
                ins4p(m[u], di, t0[u], t1[u], t2[u], t3[u], i0[u], i1[u], i2[u]);
        }
        __syncthreads();
    }
    #pragma unroll
    for (int u = 0; u < QPL; ++u) {
        int q = blockIdx.x * (TPB * QPL) + threadIdx.x + u * TPB;
        part_v[(size_t)blockIdx.y * NPTS + q] = make_float4(t0[u], t1[u], t2[u], t3[u]);
        part_i[(size_t)blockIdx.y * NPTS + q] =
            make_ushort4((unsigned short)i0[u], (unsigned short)i1[u],
                         (unsigned short)i2[u], 0);
    }
}

// ---------------------------------------------------------------------------
// K2: merge Sk partial (top-4 value, top-3 index) lists per query.
// A split's 4th value can never reach the global top-3 (within-split rank <=
// global rank), so per-split top-3 indices suffice.
// ---------------------------------------------------------------------------
__global__ __launch_bounds__(TPM) void knn_merge_kernel(
    const float4* __restrict__ part_v, const ushort4* __restrict__ part_i,
    float* __restrict__ r, float4* __restrict__ mv, ushort4* __restrict__ mi, int S)
{
    const int q = blockIdx.x * TPM + threadIdx.x;
    float t0=-1.f,t1=-1.f,t2=-1.f,t3=-1.f;
    int i0=0,i1=0,i2=0;
    for (int s = 0; s < S; ++s) {
        float4  v  = part_v[(size_t)s * NPTS + q];
        ushort4 id = part_i[(size_t)s * NPTS + q];
        ins4p(v.x, id.x, t0,t1,t2,t3, i0,i1,i2);
        ins4p(v.y, id.y, t0,t1,t2,t3, i0,i1,i2);
        ins4p(v.z, id.z, t0,t1,t2,t3, i0,i1,i2);
        ins4p(v.w, id.w, t0,t1,t2,t3, i0,i1,i2);
    }
    r[q]  = t3 - 1e-15f;   // == t3 bit-exact in f32 (fidelity to reference)
    mv[q] = make_float4(t0, t1, t2, t3);
    mi[q] = make_ushort4((unsigned short)i0, (unsigned short)i1,
                         (unsigned short)i2, 0);
}

// ---------------------------------------------------------------------------
// K3: exact counts via candidate check. Every point outside the joint top-3
// has d32 <= t3 = r, hence dx <= r and dy <= r (marginal max over a subset of
// the same exact f32 values). So nx = NPTS - #{top-3 candidates with dx > r}.
// ---------------------------------------------------------------------------
__global__ __launch_bounds__(TPM) void count_check_kernel(
    const float* __restrict__ x, const float* __restrict__ y,
    const float* __restrict__ r, const float4* __restrict__ mv,
    const ushort4* __restrict__ mi, double* __restrict__ dig)
{
    const int q = blockIdx.x * TPM + threadIdx.x;
    const float rq = r[q];
    float qv[32];
    load_query(qv, x, y, q);

    float4  v  = mv[q];
    ushort4 id = mi[q];
    float vals[3] = { v.x, v.y, v.z };
    int   idxs[3] = { (int)id.x, (int)id.y, (int)id.z };

    int missx = 0, missy = 0;
    #pragma unroll
    for (int k = 0; k < 3; ++k) {
        const int j = idxs[k];
        const float4* px4 = reinterpret_cast<const float4*>(x) + (size_t)j * 4;
        const float4* py4 = reinterpret_cast<const float4*>(y) + (size_t)j * 4;
        float mx = 0.0f, my = 0.0f;
        #pragma unroll
        for (int i = 0; i < 4; ++i) {
            float4 a = px4[i];
            mx = fmax3(mx, fmax3(fabsf(qv[4*i+0]-a.x), fabsf(qv[4*i+1]-a.y),
                                 fabsf(qv[4*i+2]-a.z)), fabsf(qv[4*i+3]-a.w));
            float4 b = py4[i];
            my = fmax3(my, fmax3(fabsf(qv[16+4*i+0]-b.x), fabsf(qv[16+4*i+1]-b.y),
                                 fabsf(qv[16+4*i+2]-b.z)), fabsf(qv[16+4*i+3]-b.w));
        }
        const bool act = vals[k] > rq;   // only strict-greater joints can be missing
        missx += (act && (mx > rq)) ? 1 : 0;
        missy += (act && (my > rq)) ? 1 : 0;
    }
    const int nx = NPTS - missx;
    const int ny = NPTS - missy;
    dig[q] = digamma_d((double)nx) + digamma_d((double)ny);
}

// ---------------------------------------------------------------------------
// K4: ans = psi(N) + psi(k) - mean(psi(nx)+psi(ny))
// (log/log2 terms of the reference cancel exactly in ans_x+ans_y-ans_xy)
// ---------------------------------------------------------------------------
__global__ __launch_bounds__(TPM) void final_kernel(
    const double* __restrict__ dig, float* __restrict__ out)
{
    __shared__ double sm[TPM];
    double s = 0.0;
    for (int i = threadIdx.x; i < NPTS; i += TPM) s += dig[i];
    sm[threadIdx.x] = s;
    __syncthreads();
    for (int w = TPM / 2; w > 0; w >>= 1) {
        if (threadIdx.x < w) sm[threadIdx.x] += sm[threadIdx.x + w];
        __syncthreads();
    }
    if (threadIdx.x == 0) {
        double ans = digamma_d((double)NPTS) + digamma_d(4.0) - sm[0] / (double)NPTS;
        out[0] = (float)ans;
    }
}

// ---------------------------------------------------------------------------
extern "C" void kernel_launch(void* const* d_in, const int* in_sizes, int n_in,
                              void* d_out, int out_size, void* d_ws, size_t ws_size,
                              hipStream_t stream)
{
    (void)in_sizes; (void)n_in; (void)out_size;
    const float* x = (const float*)d_in[0];
    const float* y = (const float*)d_in[1];
    float* out = (float*)d_out;

    // workspace: dig (NPTS f64) | r (NPTS f32) | mv (NPTS float4) | mi (NPTS ushort4)
    //            | part_v (Sk*NPTS float4) | part_i (Sk*NPTS ushort4)
    char* ws = (char*)d_ws;
    double*  dig = (double*)ws;
    float*   r   = (float*)(ws + (size_t)NPTS * 8);
    float4*  mv  = (float4*)(ws + (size_t)NPTS * 16);          // 16B aligned
    ushort4* mi  = (ushort4*)(ws + (size_t)NPTS * 32);
    char*    p0  = ws + (size_t)NPTS * 40;                     // 16B aligned

    int Sk = 128;
    auto need = [&](int sk) {
        return (size_t)(p0 - ws) + (size_t)sk * NPTS * 24;
    };
    while (Sk > 32 && need(Sk) > ws_size) Sk >>= 1;

    float4*  part_v = (float4*)p0;
    ushort4* part_i = (ushort4*)(p0 + (size_t)Sk * NPTS * 16);
    const int pps = NPTS / Sk;   // multiple of TILE for Sk<=128

    dim3 gridK(NPTS / (TPB * QPL), Sk);   // (16,128) = 2048 blocks = 8192 waves
    knn_part_kernel<<<gridK, TPB, 0, stream>>>(x, y, part_v, part_i, pps);
    knn_merge_kernel<<<NPTS / TPM, TPM, 0, stream>>>(part_v, part_i, r, mv, mi, Sk);
    count_check_kernel<<<NPTS / TPM, TPM, 0, stream>>>(x, y, r, mv, mi, dig);
    final_kernel<<<1, TPM, 0, stream>>>(dig, out);
}

// Round 9
// 168.752 us; speedup vs baseline: 2.3283x; 1.2847x over previous
//
#include <hip/hip_runtime.h>
#include <math.h>

#define NPTS 8192
#define TPB  256          // threads per block, knn kernel
#define QPL  2            // queries per lane
#define TILE 64           // points staged per LDS tile (8 KB f32)
#define TPM  256          // threads per block, merge/final kernels
#define QPB_M 32          // queries per merge block
#define NCHUNK 8          // split-chunks per merge block

__device__ __forceinline__ float fmax3(float a, float b, float c) {
    return fmaxf(fmaxf(a, b), c);   // folds to v_max3_f32 (abs modifiers at leaves)
}

// Branchless sorted-descending top-4 insert with index payload on levels 0-2.
// (level 3 value-only: only indices with value > t3 are ever needed)
__device__ __forceinline__ void ins4p(float d, int di,
    float& t0, float& t1, float& t2, float& t3,
    int& i0, int& i1, int& i2)
{
    bool c0 = d > t0;
    float v1 = fminf(t0, d); int j1 = c0 ? i0 : di;
    t0 = fmaxf(t0, d);       i0 = c0 ? i0 : di;
    bool c1 = v1 > t1;
    float v2 = fminf(t1, v1); int j2 = c1 ? i1 : j1;
    t1 = fmaxf(t1, v1);       i1 = c1 ? j1 : i1;
    bool c2 = v2 > t2;
    float v3 = fminf(t2, v2);
    t2 = fmaxf(t2, v2);       i2 = c2 ? j2 : i2;
    t3 = fmaxf(t3, v3);
}

__device__ double digamma_d(double x) {
    double r = 0.0;
    while (x < 6.0) { r -= 1.0 / x; x += 1.0; }   // psi(4) in final kernel only
    double f = 1.0 / (x * x);
    double t = f * (1.0/12.0 - f * (1.0/120.0 - f * (1.0/252.0 - f * (1.0/240.0 - f * (1.0/132.0)))));
    return r + log(x) - 0.5 / x - t;
}

// Cooperative stage of TILE points (x:16 + y:16 floats) into LDS.
__device__ __forceinline__ void stage_tile(
    float4* pts4, const float* __restrict__ x, const float* __restrict__ y, int jt)
{
    #pragma unroll
    for (int i = 0; i < (TILE * 8) / TPB; ++i) {
        int li = i * TPB + threadIdx.x;
        int pt = li >> 3, c = li & 7;
        const float4* src = (c < 4)
            ? reinterpret_cast<const float4*>(x) + (size_t)(jt + pt) * 4 + c
            : reinterpret_cast<const float4*>(y) + (size_t)(jt + pt) * 4 + (c - 4);
        pts4[li] = *src;
    }
}

__device__ __forceinline__ void load_query(float* qv, const float* __restrict__ x,
                                           const float* __restrict__ y, int q)
{
    const float4* qx4 = reinterpret_cast<const float4*>(x) + (size_t)q * 4;
    const float4* qy4 = reinterpret_cast<const float4*>(y) + (size_t)q * 4;
    #pragma unroll
    for (int i = 0; i < 4; ++i) {
        float4 v = qx4[i];
        qv[4*i+0] = v.x; qv[4*i+1] = v.y; qv[4*i+2] = v.z; qv[4*i+3] = v.w;
        float4 w = qy4[i];
        qv[16+4*i+0] = w.x; qv[16+4*i+1] = w.y; qv[16+4*i+2] = w.z; qv[16+4*i+3] = w.w;
    }
}

// ---------------------------------------------------------------------------
// K1: per-query partial top-4 (values) + top-3 (indices) of joint Chebyshev
// distance over a point split. grid = (NPTS/(TPB*QPL), Sk). R8-proven: 106 us.
// ---------------------------------------------------------------------------
__global__ __launch_bounds__(TPB, 2) void knn_part_kernel(
    const float* __restrict__ x, const float* __restrict__ y,
    float4* __restrict__ part_v, ushort4* __restrict__ part_i, int pps)
{
    __shared__ float4 pts4[TILE * 8];
    float qv[QPL][32];
    float t0[QPL], t1[QPL], t2[QPL], t3[QPL];
    int   i0[QPL], i1[QPL], i2[QPL];
    #pragma unroll
    for (int u = 0; u < QPL; ++u) {
        load_query(qv[u], x, y, blockIdx.x * (TPB * QPL) + threadIdx.x + u * TPB);
        t0[u] = t1[u] = t2[u] = t3[u] = -1.0f;
        i0[u] = i1[u] = i2[u] = 0;
    }

    const int j0 = blockIdx.y * pps;
    for (int jt = j0; jt < j0 + pps; jt += TILE) {
        stage_tile(pts4, x, y, jt);
        __syncthreads();
        #pragma unroll 2
        for (int jj = 0; jj < TILE; ++jj) {
            const float4* pj = &pts4[jj * 8];
            float m[QPL];
            #pragma unroll
            for (int u = 0; u < QPL; ++u) m[u] = 0.0f;   // distances >= 0
            #pragma unroll
            for (int i = 0; i < 8; ++i) {
                float4 v = pj[i];                         // wave-uniform broadcast
                #pragma unroll
                for (int u = 0; u < QPL; ++u) {
                    float d0 = qv[u][4*i+0] - v.x;
                    float d1 = qv[u][4*i+1] - v.y;
                    float d2 = qv[u][4*i+2] - v.z;
                    float d3 = qv[u][4*i+3] - v.w;
                    m[u] = fmax3(m[u], fmax3(fabsf(d0), fabsf(d1), fabsf(d2)), fabsf(d3));
                }
            }
            const int di = jt + jj;
            #pragma unroll
            for (int u = 0; u < QPL; ++u)
                ins4p(m[u], di, t0[u], t1[u], t2[u], t3[u], i0[u], i1[u], i2[u]);
        }
        __syncthreads();
    }
    #pragma unroll
    for (int u = 0; u < QPL; ++u) {
        int q = blockIdx.x * (TPB * QPL) + threadIdx.x + u * TPB;
        part_v[(size_t)blockIdx.y * NPTS + q] = make_float4(t0[u], t1[u], t2[u], t3[u]);
        part_i[(size_t)blockIdx.y * NPTS + q] =
            make_ushort4((unsigned short)i0[u], (unsigned short)i1[u],
                         (unsigned short)i2[u], 0);
    }
}

// ---------------------------------------------------------------------------
// K2 (fused): two-stage merge of Sk partials + candidate count + digamma.
// Stage 1: 8 chunks x 32 queries per block, each thread merges S/8 splits.
// Stage 2: chunk-0 lanes merge the 8 chunk-partials from LDS, then do the
// exact 3-candidate check (every point outside the joint top-3 has
// d_joint <= t3 = r, hence dx <= r and dy <= r bit-exactly) and write dig[q].
// Index-less 4th values are safe: a split's top-3 are inserted before its
// 4th by the same thread, so the 4th never occupies an index-bearing slot.
// ---------------------------------------------------------------------------
__global__ __launch_bounds__(TPM) void merge_check_kernel(
    const float4* __restrict__ part_v, const ushort4* __restrict__ part_i,
    const float* __restrict__ x, const float* __restrict__ y,
    double* __restrict__ dig, int S)
{
    __shared__ float4  sv[NCHUNK][QPB_M];
    __shared__ ushort4 si[NCHUNK][QPB_M];
    const int ql = threadIdx.x & (QPB_M - 1);
    const int ck = threadIdx.x / QPB_M;          // 0..7
    const int q  = blockIdx.x * QPB_M + ql;
    const int cl = S / NCHUNK;

    float t0=-1.f,t1=-1.f,t2=-1.f,t3=-1.f;
    int i0=0,i1=0,i2=0;
    for (int k = 0; k < cl; ++k) {
        const int s = ck * cl + k;
        float4  v  = part_v[(size_t)s * NPTS + q];
        ushort4 id = part_i[(size_t)s * NPTS + q];
        ins4p(v.x, id.x, t0,t1,t2,t3, i0,i1,i2);
        ins4p(v.y, id.y, t0,t1,t2,t3, i0,i1,i2);
        ins4p(v.z, id.z, t0,t1,t2,t3, i0,i1,i2);
        ins4p(v.w, 0,    t0,t1,t2,t3, i0,i1,i2);  // 4th: value-only
    }
    sv[ck][ql] = make_float4(t0, t1, t2, t3);
    si[ck][ql] = make_ushort4((unsigned short)i0, (unsigned short)i1,
                              (unsigned short)i2, 0);
    __syncthreads();

    if (ck == 0) {
        #pragma unroll
        for (int c = 1; c < NCHUNK; ++c) {
            float4  v  = sv[c][ql];
            ushort4 id = si[c][ql];
            ins4p(v.x, id.x, t0,t1,t2,t3, i0,i1,i2);
            ins4p(v.y, id.y, t0,t1,t2,t3, i0,i1,i2);
            ins4p(v.z, id.z, t0,t1,t2,t3, i0,i1,i2);
            ins4p(v.w, 0,    t0,t1,t2,t3, i0,i1,i2);
        }
        const float rq = t3 - 1e-15f;  // == t3 bit-exact in f32 (reference fidelity)

        float qv[32];
        load_query(qv, x, y, q);

        float vals[3] = { t0, t1, t2 };
        int   idxs[3] = { i0, i1, i2 };
        int missx = 0, missy = 0;
        #pragma unroll
        for (int k = 0; k < 3; ++k) {
            const int j = idxs[k];
            const float4* px4 = reinterpret_cast<const float4*>(x) + (size_t)j * 4;
            const float4* py4 = reinterpret_cast<const float4*>(y) + (size_t)j * 4;
            float mx = 0.0f, my = 0.0f;
            #pragma unroll
            for (int i = 0; i < 4; ++i) {
                float4 a = px4[i];
                mx = fmax3(mx, fmax3(fabsf(qv[4*i+0]-a.x), fabsf(qv[4*i+1]-a.y),
                                     fabsf(qv[4*i+2]-a.z)), fabsf(qv[4*i+3]-a.w));
                float4 b = py4[i];
                my = fmax3(my, fmax3(fabsf(qv[16+4*i+0]-b.x), fabsf(qv[16+4*i+1]-b.y),
                                     fabsf(qv[16+4*i+2]-b.z)), fabsf(qv[16+4*i+3]-b.w));
            }
            const bool act = vals[k] > rq;   // only strict-greater joints can miss
            missx += (act && (mx > rq)) ? 1 : 0;
            missy += (act && (my > rq)) ? 1 : 0;
        }
        const int nx = NPTS - missx;
        const int ny = NPTS - missy;
        dig[q] = digamma_d((double)nx) + digamma_d((double)ny);
    }
}

// ---------------------------------------------------------------------------
// K3: ans = psi(N) + psi(k) - mean(psi(nx)+psi(ny))
// (log/log2 terms of the reference cancel exactly in ans_x+ans_y-ans_xy)
// ---------------------------------------------------------------------------
__global__ __launch_bounds__(TPM) void final_kernel(
    const double* __restrict__ dig, float* __restrict__ out)
{
    __shared__ double sm[TPM];
    double s = 0.0;
    for (int i = threadIdx.x; i < NPTS; i += TPM) s += dig[i];
    sm[threadIdx.x] = s;
    __syncthreads();
    for (int w = TPM / 2; w > 0; w >>= 1) {
        if (threadIdx.x < w) sm[threadIdx.x] += sm[threadIdx.x + w];
        __syncthreads();
    }
    if (threadIdx.x == 0) {
        double ans = digamma_d((double)NPTS) + digamma_d(4.0) - sm[0] / (double)NPTS;
        out[0] = (float)ans;
    }
}

// ---------------------------------------------------------------------------
extern "C" void kernel_launch(void* const* d_in, const int* in_sizes, int n_in,
                              void* d_out, int out_size, void* d_ws, size_t ws_size,
                              hipStream_t stream)
{
    (void)in_sizes; (void)n_in; (void)out_size;
    const float* x = (const float*)d_in[0];
    const float* y = (const float*)d_in[1];
    float* out = (float*)d_out;

    // workspace: dig (NPTS f64) | part_v (Sk*NPTS float4) | part_i (Sk*NPTS ushort4)
    char* ws = (char*)d_ws;
    double* dig = (double*)ws;
    char*   p0  = ws + (size_t)NPTS * 8;     // 16B aligned

    int Sk = 128;
    auto need = [&](int sk) {
        return (size_t)(p0 - ws) + (size_t)sk * NPTS * 24;
    };
    while (Sk > 32 && need(Sk) > ws_size) Sk >>= 1;

    float4*  part_v = (float4*)p0;
    ushort4* part_i = (ushort4*)(p0 + (size_t)Sk * NPTS * 16);
    const int pps = NPTS / Sk;   // multiple of TILE for Sk<=128

    dim3 gridK(NPTS / (TPB * QPL), Sk);   // (16,128) = 2048 blocks = 8192 waves
    knn_part_kernel<<<gridK, TPB, 0, stream>>>(x, y, part_v, part_i, pps);
    merge_check_kernel<<<NPTS / QPB_M, TPM, 0, stream>>>(part_v, part_i, x, y, dig, Sk);
    final_kernel<<<1, TPM, 0, stream>>>(dig, out);
}